// Round 11
// baseline (509.927 us; speedup 1.0000x reference)
//
#include <hip/hip_runtime.h>
#include <hip/hip_bf16.h>
#include <math.h>

#define NN 512   // hidden states
#define MM 256   // timesteps / emission symbols
#define BB 128   // batch

typedef float        f32x4 __attribute__((ext_vector_type(4)));
typedef unsigned int u32;
typedef u32          u32x2 __attribute__((ext_vector_type(2)));
typedef unsigned long long u64;
typedef u64          u64x2 __attribute__((ext_vector_type(2)));

#define LOG16F 2.772588722239781f

__device__ __forceinline__ float wave_max(float v) {
#pragma unroll
    for (int o = 32; o > 0; o >>= 1) v = fmaxf(v, __shfl_xor(v, o));
    return v;
}
__device__ __forceinline__ float wave_sum(float v) {
#pragma unroll
    for (int o = 32; o > 0; o >>= 1) v += __shfl_xor(v, o);
    return v;
}

// Permuted LDS address for u-hat so B-reads are 16B-contiguous:
// byte position (p,h,j2) of a ds_read_b128 at p*64+h*16 carries exactly
// state i == k (identity on the MFMA k-map).  addr(i):
__device__ __forceinline__ int uaddr(int i) {
    return (i & 0x1C0) | (((i >> 3) & 3) << 4) | (((i >> 5) & 1) << 3) | (i & 7);
}

// ---------------- preprocessing ----------------

// Column-wise logsumexp of T (log_softmax axis=0 denominator). grid 8 x 64.
__global__ void k_col_lse(const float* __restrict__ T, float* __restrict__ c) {
    int k = blockIdx.x * 64 + threadIdx.x;
    float m = -INFINITY, s = 0.f;
    for (int i = 0; i < NN; ++i) {
        float x = T[i * NN + k];
        if (x > m) { s = s * __expf(m - x) + 1.f; m = x; }
        else       { s += __expf(x - m); }
    }
    c[k] = m + __logf(s);
}

// Row max: M[i] = max_k(T[i,k]-c[k]) - log(64). grid 512 x 64.
__global__ void k_rowM(const float* __restrict__ T, const float* __restrict__ c,
                       float* __restrict__ M) {
    int i = blockIdx.x, j = threadIdx.x;
    float mx = -INFINITY;
#pragma unroll
    for (int d = 0; d < 8; ++d) {
        int k = j * 8 + d;
        mx = fmaxf(mx, T[i * NN + k] - c[k]);
    }
    mx = wave_max(mx);
    if (j == 0) M[i] = mx - __logf(64.f);
}

// C_M = max_i M[i]. grid 1 x 512.
__global__ void k_cm(const float* __restrict__ M, float* __restrict__ CM) {
    __shared__ float red[8];
    int i = threadIdx.x;
    float wm = wave_max(M[i]);
    if ((i & 63) == 0) red[i >> 6] = wm;
    __syncthreads();
    if (i == 0) {
        float m = red[0];
#pragma unroll
        for (int j = 1; j < 8; ++j) m = fmaxf(m, red[j]);
        CM[0] = m;
    }
}

// lp2[i] = exp(log_softmax(pr)[i] - M[i] + C_M + log16). grid 1 x 512.
__global__ void k_priors(const float* __restrict__ pr, const float* __restrict__ M,
                         const float* __restrict__ CM, float* __restrict__ lp2) {
    __shared__ float red[8];
    int i = threadIdx.x;
    float x = pr[i];
    float wm = wave_max(x);
    if ((i & 63) == 0) red[i >> 6] = wm;
    __syncthreads();
    float m = red[0];
#pragma unroll
    for (int j = 1; j < 8; ++j) m = fmaxf(m, red[j]);
    float e = __expf(x - m);
    float ws = wave_sum(e);
    __syncthreads();
    if ((i & 63) == 0) red[i >> 6] = ws;
    __syncthreads();
    float S = red[0];
#pragma unroll
    for (int j = 1; j < 8; ++j) S += red[j];
    float lp = x - (m + __logf(S));
    lp2[i] = __expf(lp - M[i] + CM[0] + LOG16F);
}

// Pack P into fp8 MFMA A-fragments, scaled x64 (row max -> 64).
// Fragment (tile,kc): lane l holds 8 bytes = P[row=tile*16+(l&15),
// k=kc*32+(l>>4)*8+j]. Stored as u64 at PA8[(tile*16+kc)*64+l].
__global__ void k_packA(const float* __restrict__ T, const float* __restrict__ c,
                        const float* __restrict__ M, u32* __restrict__ PA) {
    int blk = blockIdx.x, l = threadIdx.x;
    int tile = blk >> 4, kc = blk & 15;
    int row = tile * 16 + (l & 15);
    int kb  = kc * 32 + (l >> 4) * 8;
    float Mi = M[row];                    // = rowmax - log64
    float p[8];
#pragma unroll
    for (int j = 0; j < 8; ++j)
        p[j] = __expf(T[row * NN + kb + j] - c[kb + j] - Mi);   // <= 64
    int d0 = 0, d1 = 0;
    d0 = __builtin_amdgcn_cvt_pk_fp8_f32(p[0], p[1], d0, false);
    d0 = __builtin_amdgcn_cvt_pk_fp8_f32(p[2], p[3], d0, true);
    d1 = __builtin_amdgcn_cvt_pk_fp8_f32(p[4], p[5], d1, false);
    d1 = __builtin_amdgcn_cvt_pk_fp8_f32(p[6], p[7], d1, true);
    u32x2 st = { (u32)d0, (u32)d1 };
    *(u32x2*)(PA + ((size_t)blk * 64 + l) * 2) = st;
}

// Row i of E: log-softmax + fold the scan's exp:
// EX[m*NN+i] = exp(logE[i,m] + M[i] - C_M - log16). grid 512 x 64.
__global__ void k_rowEX(const float* __restrict__ E, const float* __restrict__ M,
                        const float* __restrict__ CM, float* __restrict__ EX) {
    int i = blockIdx.x, j = threadIdx.x;
    float v[4];
    float mx = -INFINITY;
#pragma unroll
    for (int d = 0; d < 4; ++d) {
        v[d] = E[i * MM + j * 4 + d];
        mx = fmaxf(mx, v[d]);
    }
    mx = wave_max(mx);
    float s = 0.f;
#pragma unroll
    for (int d = 0; d < 4; ++d) s += __expf(v[d] - mx);
    s = wave_sum(s);
    float lse = mx + __logf(s);
    float add = M[i] - CM[0] - LOG16F - lse;
#pragma unroll
    for (int d = 0; d < 4; ++d)
        EX[(size_t)(j * 4 + d) * NN + i] = __expf(v[d] + add);
}

// ---------------- the scan ----------------
// One block per batch, 512 threads = 8 waves. Wave w owns i-tiles w*4..w*4+3.
// P fp8 A-frags pinned in AGPRs (MFMA reads AGPR A-operands directly on
// gfx950). u-hat fp8 in permuted LDS layout (8 x ds_read_b128 per step).
// Fresh scale 16/S_t. Prefetch: obs/EX row for t+1 loaded during step t.
// log S / out / K deferred past B2 (overlap next step's MFMA).
__global__ __launch_bounds__(512, 2) void k_scan(
        const int* __restrict__ obs, const float* __restrict__ lp2,
        const float* __restrict__ CM, const u32* __restrict__ PAu,
        const float* __restrict__ EX, float* __restrict__ out) {
    int b = blockIdx.x, tid = threadIdx.x;
    int w = tid >> 6, l = tid & 63;
    int h16 = (l >> 4) * 16;              // byte offset of this lane's B slice
    int r4 = (l >> 4) * 4;                // row group within a 16-row tile
    __shared__ unsigned char us8[NN] __attribute__((aligned(16)));
    __shared__ float rB[8] __attribute__((aligned(16)));
    __shared__ int obs_s[MM];
    if (tid < MM) obs_s[tid] = obs[b * MM + tid];

    // --- stage A-fragments: 64 x u64 per lane (4 tiles x 16 k-chunks) ---
    const u64* PA8 = (const u64*)PAu;
    u64 pa[64];
#pragma unroll
    for (int ti = 0; ti < 4; ++ti)
#pragma unroll
        for (int kc = 0; kc < 16; ++kc)
            pa[ti * 16 + kc] = PA8[(size_t)(((w * 4 + ti) * 16 + kc)) * 64 + l];
#pragma unroll
    for (int q = 0; q < 64; ++q) asm volatile("" : "+a"(pa[q]));  // AGPR-resident

    float C_M = CM[0];
    int ubase[4];                          // publish byte addresses (u32-aligned)
#pragma unroll
    for (int ti = 0; ti < 4; ++ti) ubase[ti] = uaddr((w * 4 + ti) * 16 + r4);
    __syncthreads();                      // obs_s ready

    // ---- t = 0: e = EX[o0] * lp2 ----
    int o0 = obs_s[0];
    f32x4 e4[4];
    float loc = 0.f;
#pragma unroll
    for (int ti = 0; ti < 4; ++ti) {
        f32x4 ex  = *(const f32x4*)(EX  + (size_t)o0 * NN + (w * 4 + ti) * 16 + r4);
        f32x4 lpv = *(const f32x4*)(lp2 + (w * 4 + ti) * 16 + r4);
#pragma unroll
        for (int r = 0; r < 4; ++r) {
            float e = ex[r] * lpv[r];
            e4[ti][r] = e; loc += e;
        }
    }
    loc += __shfl_xor(loc, 16);
    loc += __shfl_xor(loc, 32);
    if (l == 0) rB[w] = loc;
    __syncthreads();                      // B1
    f32x4 sv0 = *(const f32x4*)rB;
    f32x4 sv1 = *(const f32x4*)(rB + 4);
    float S = (sv0[0] + sv0[1]) + (sv0[2] + sv0[3])
            + (sv1[0] + sv1[1]) + (sv1[2] + sv1[3]);
    S = fmaxf(S, 1e-35f);
    float sc = __builtin_amdgcn_rcpf(S) * 16.f;
    if ((l & 15) == 0) {
#pragma unroll
        for (int ti = 0; ti < 4; ++ti) {
            int d = 0;
            d = __builtin_amdgcn_cvt_pk_fp8_f32(e4[ti][0] * sc, e4[ti][1] * sc, d, false);
            d = __builtin_amdgcn_cvt_pk_fp8_f32(e4[ti][2] * sc, e4[ti][3] * sc, d, true);
            *(u32*)&us8[ubase[ti]] = (u32)d;
        }
    }
    __syncthreads();                      // B2: us8 ready
    float lS = __logf(S);
    if (tid == 0) out[(size_t)b * MM + 0] = lS;
    float K = C_M + lS;                   // Omega_1

    // prefetch t=1 emission row
    f32x4 exn[4];
    {
        int on = obs_s[1];
#pragma unroll
        for (int ti = 0; ti < 4; ++ti)
            exn[ti] = *(const f32x4*)(EX + (size_t)on * NN + (w * 4 + ti) * 16 + r4);
    }

    // ---- main scan t >= 1 ----
#pragma unroll 1
    for (int t = 1; t < MM; ++t) {
        const unsigned char* ub = us8;
        f32x4 aA0 = {0.f,0.f,0.f,0.f}, aA1 = {0.f,0.f,0.f,0.f};
        f32x4 aA2 = {0.f,0.f,0.f,0.f}, aA3 = {0.f,0.f,0.f,0.f};
        f32x4 aB0 = {0.f,0.f,0.f,0.f}, aB1 = {0.f,0.f,0.f,0.f};
        f32x4 aB2 = {0.f,0.f,0.f,0.f}, aB3 = {0.f,0.f,0.f,0.f};
        __builtin_amdgcn_s_setprio(1);
#pragma unroll
        for (int p = 0; p < 8; ++p) {      // 8 x ds_read_b128, 8 chains depth 8
            u64x2 bb = *(const u64x2*)(ub + p * 64 + h16);
            int kc0 = 2 * p, kc1 = 2 * p + 1;
            aA0 = __builtin_amdgcn_mfma_f32_16x16x32_fp8_fp8((long)pa[0*16+kc0], (long)bb.x, aA0, 0, 0, 0);
            aA1 = __builtin_amdgcn_mfma_f32_16x16x32_fp8_fp8((long)pa[1*16+kc0], (long)bb.x, aA1, 0, 0, 0);
            aA2 = __builtin_amdgcn_mfma_f32_16x16x32_fp8_fp8((long)pa[2*16+kc0], (long)bb.x, aA2, 0, 0, 0);
            aA3 = __builtin_amdgcn_mfma_f32_16x16x32_fp8_fp8((long)pa[3*16+kc0], (long)bb.x, aA3, 0, 0, 0);
            aB0 = __builtin_amdgcn_mfma_f32_16x16x32_fp8_fp8((long)pa[0*16+kc1], (long)bb.y, aB0, 0, 0, 0);
            aB1 = __builtin_amdgcn_mfma_f32_16x16x32_fp8_fp8((long)pa[1*16+kc1], (long)bb.y, aB1, 0, 0, 0);
            aB2 = __builtin_amdgcn_mfma_f32_16x16x32_fp8_fp8((long)pa[2*16+kc1], (long)bb.y, aB2, 0, 0, 0);
            aB3 = __builtin_amdgcn_mfma_f32_16x16x32_fp8_fp8((long)pa[3*16+kc1], (long)bb.y, aB3, 0, 0, 0);
        }
        __builtin_amdgcn_s_setprio(0);
        f32x4 sacc[4] = { aA0 + aB0, aA1 + aB1, aA2 + aB2, aA3 + aB3 };

        // e = ex * s_raw (ex was prefetched last step)
        loc = 0.f;
#pragma unroll
        for (int ti = 0; ti < 4; ++ti)
#pragma unroll
            for (int r = 0; r < 4; ++r) {
                float e = exn[ti][r] * sacc[ti][r];
                e4[ti][r] = e; loc += e;
            }

        // prefetch t+1 emission row (hidden under reduce/barriers/publish)
        int on = obs_s[(t + 1 < MM) ? t + 1 : t];
#pragma unroll
        for (int ti = 0; ti < 4; ++ti)
            exn[ti] = *(const f32x4*)(EX + (size_t)on * NN + (w * 4 + ti) * 16 + r4);

        loc += __shfl_xor(loc, 16);
        loc += __shfl_xor(loc, 32);
        if (l == 0) rB[w] = loc;
        __syncthreads();                  // B1: rB ready (us8 reads done too)
        sv0 = *(const f32x4*)rB;
        sv1 = *(const f32x4*)(rB + 4);
        S = (sv0[0] + sv0[1]) + (sv0[2] + sv0[3])
          + (sv1[0] + sv1[1]) + (sv1[2] + sv1[3]);
        S = fmaxf(S, 1e-35f);
        sc = __builtin_amdgcn_rcpf(S) * 16.f;
        if ((l & 15) == 0) {
#pragma unroll
            for (int ti = 0; ti < 4; ++ti) {
                int d = 0;
                d = __builtin_amdgcn_cvt_pk_fp8_f32(e4[ti][0] * sc, e4[ti][1] * sc, d, false);
                d = __builtin_amdgcn_cvt_pk_fp8_f32(e4[ti][2] * sc, e4[ti][3] * sc, d, true);
                *(u32*)&us8[ubase[ti]] = (u32)d;
            }
        }
        __syncthreads();                  // B2: us8 ready for next step
        // deferred bookkeeping (overlaps next step's MFMA)
        float lSn = __logf(S);
        if (tid == 0) out[(size_t)b * MM + t] = K + lSn;
        K += C_M + lSn;                   // Omega_{t+1}
    }
}

extern "C" void kernel_launch(void* const* d_in, const int* in_sizes, int n_in,
                              void* d_out, int out_size, void* d_ws, size_t ws_size,
                              hipStream_t stream) {
    const int*   obs = (const int*)d_in[0];
    const float* pri = (const float*)d_in[1];
    const float* T   = (const float*)d_in[2];
    const float* E   = (const float*)d_in[3];
    float* out = (float*)d_out;
    char* ws = (char*)d_ws;

    float* c   = (float*)(ws + 0);
    float* lp2 = (float*)(ws + 2048);
    float* M   = (float*)(ws + 4096);
    float* CM  = (float*)(ws + 6144);
    u32*   PA  = (u32*)(ws + 8192);                       // 256 KB fp8 A-frags
    float* EX  = (float*)(ws + 8192 + 256 * 1024);        // 512 KB

    k_col_lse<<<8,   64, 0, stream>>>(T, c);
    k_rowM   <<<512, 64, 0, stream>>>(T, c, M);
    k_cm     <<<1,  512, 0, stream>>>(M, CM);
    k_priors <<<1,  512, 0, stream>>>(pri, M, CM, lp2);
    k_packA  <<<512, 64, 0, stream>>>(T, c, M, PA);
    k_rowEX  <<<512, 64, 0, stream>>>(E, M, CM, EX);
    k_scan   <<<BB, 512, 0, stream>>>(obs, lp2, CM, PA, EX, out);
}

// Round 12
// 390.724 us; speedup vs baseline: 1.3051x; 1.3051x over previous
//
#include <hip/hip_runtime.h>
#include <hip/hip_bf16.h>
#include <math.h>

#define NN 512   // hidden states
#define MM 256   // timesteps / emission symbols
#define BB 128   // batch

typedef float        f32x4 __attribute__((ext_vector_type(4)));
typedef unsigned int u32;
typedef u32          u32x2 __attribute__((ext_vector_type(2)));
typedef unsigned long long u64;
typedef int          i32x8 __attribute__((ext_vector_type(8)));

#define LOG16F 2.772588722239781f
#define SCL1   0x7F   // E8M0 scale byte = 1.0

__device__ __forceinline__ float wave_max(float v) {
#pragma unroll
    for (int o = 32; o > 0; o >>= 1) v = fmaxf(v, __shfl_xor(v, o));
    return v;
}
__device__ __forceinline__ float wave_sum(float v) {
#pragma unroll
    for (int o = 32; o > 0; o >>= 1) v += __shfl_xor(v, o);
    return v;
}

// ---------------- preprocessing ----------------

// Column-wise logsumexp of T (log_softmax axis=0 denominator). grid 8 x 64.
__global__ void k_col_lse(const float* __restrict__ T, float* __restrict__ c) {
    int k = blockIdx.x * 64 + threadIdx.x;
    float m = -INFINITY, s = 0.f;
    for (int i = 0; i < NN; ++i) {
        float x = T[i * NN + k];
        if (x > m) { s = s * __expf(m - x) + 1.f; m = x; }
        else       { s += __expf(x - m); }
    }
    c[k] = m + __logf(s);
}

// Row max: M[i] = max_k(T[i,k]-c[k]) - log(64). grid 512 x 64.
__global__ void k_rowM(const float* __restrict__ T, const float* __restrict__ c,
                       float* __restrict__ M) {
    int i = blockIdx.x, j = threadIdx.x;
    float mx = -INFINITY;
#pragma unroll
    for (int d = 0; d < 8; ++d) {
        int k = j * 8 + d;
        mx = fmaxf(mx, T[i * NN + k] - c[k]);
    }
    mx = wave_max(mx);
    if (j == 0) M[i] = mx - __logf(64.f);
}

// C_M = max_i M[i]. grid 1 x 512.
__global__ void k_cm(const float* __restrict__ M, float* __restrict__ CM) {
    __shared__ float red[8];
    int i = threadIdx.x;
    float wm = wave_max(M[i]);
    if ((i & 63) == 0) red[i >> 6] = wm;
    __syncthreads();
    if (i == 0) {
        float m = red[0];
#pragma unroll
        for (int j = 1; j < 8; ++j) m = fmaxf(m, red[j]);
        CM[0] = m;
    }
}

// lp2[i] = exp(log_softmax(pr)[i] - M[i] + C_M + log16). grid 1 x 512.
__global__ void k_priors(const float* __restrict__ pr, const float* __restrict__ M,
                         const float* __restrict__ CM, float* __restrict__ lp2) {
    __shared__ float red[8];
    int i = threadIdx.x;
    float x = pr[i];
    float wm = wave_max(x);
    if ((i & 63) == 0) red[i >> 6] = wm;
    __syncthreads();
    float m = red[0];
#pragma unroll
    for (int j = 1; j < 8; ++j) m = fmaxf(m, red[j]);
    float e = __expf(x - m);
    float ws = wave_sum(e);
    __syncthreads();
    if ((i & 63) == 0) red[i >> 6] = ws;
    __syncthreads();
    float S = red[0];
#pragma unroll
    for (int j = 1; j < 8; ++j) S += red[j];
    float lp = x - (m + __logf(S));
    lp2[i] = __expf(lp - M[i] + CM[0] + LOG16F);
}

// Pack P into fp8 A-fragments for mfma_scale 16x16x128 (K=128), scaled x64.
// Fragment (tile,kc): lane l holds 32 bytes = P[row=tile*16+(l&15),
// k=kc*128+(l>>4)*32+j], j=0..31 ascending (linear k-map, matches B reads).
// Stored as i32x8 at PA + ((tile*4+kc)*64+l)*8 dwords. grid 128 x 64.
__global__ void k_packA(const float* __restrict__ T, const float* __restrict__ c,
                        const float* __restrict__ M, u32* __restrict__ PA) {
    int blk = blockIdx.x, l = threadIdx.x;
    int tile = blk >> 2, kc = blk & 3;
    int row = tile * 16 + (l & 15);
    int kb  = kc * 128 + (l >> 4) * 32;
    float Mi = M[row];                    // = rowmax - log64
    i32x8 dd;
#pragma unroll
    for (int q = 0; q < 8; ++q) {
        float p0 = __expf(T[row * NN + kb + 4*q + 0] - c[kb + 4*q + 0] - Mi);
        float p1 = __expf(T[row * NN + kb + 4*q + 1] - c[kb + 4*q + 1] - Mi);
        float p2 = __expf(T[row * NN + kb + 4*q + 2] - c[kb + 4*q + 2] - Mi);
        float p3 = __expf(T[row * NN + kb + 4*q + 3] - c[kb + 4*q + 3] - Mi);
        int d = 0;
        d = __builtin_amdgcn_cvt_pk_fp8_f32(p0, p1, d, false);
        d = __builtin_amdgcn_cvt_pk_fp8_f32(p2, p3, d, true);
        dd[q] = d;
    }
    *(i32x8*)(PA + ((size_t)blk * 64 + l) * 8) = dd;
}

// Row i of E: log-softmax + fold the scan's exp:
// EX[m*NN+i] = exp(logE[i,m] + M[i] - C_M - log16). grid 512 x 64.
__global__ void k_rowEX(const float* __restrict__ E, const float* __restrict__ M,
                        const float* __restrict__ CM, float* __restrict__ EX) {
    int i = blockIdx.x, j = threadIdx.x;
    float v[4];
    float mx = -INFINITY;
#pragma unroll
    for (int d = 0; d < 4; ++d) {
        v[d] = E[i * MM + j * 4 + d];
        mx = fmaxf(mx, v[d]);
    }
    mx = wave_max(mx);
    float s = 0.f;
#pragma unroll
    for (int d = 0; d < 4; ++d) s += __expf(v[d] - mx);
    s = wave_sum(s);
    float lse = mx + __logf(s);
    float add = M[i] - CM[0] - LOG16F - lse;
#pragma unroll
    for (int d = 0; d < 4; ++d)
        EX[(size_t)(j * 4 + d) * NN + i] = __expf(v[d] + add);
}

// ---------------- the scan (MX K=128 MFMA) ----------------
// One block per batch, 512 threads = 8 waves. Wave w owns i-tiles w*4..w*4+3.
// 16 mfma_scale_f32_16x16x128_f8f6f4 per wave per step (scales = 1.0 exact),
// A-frags AGPR-resident, u-hat fp8 LINEAR in LDS (B lane reads 32 consecutive
// bytes). Fresh scale 16/S_t. EX prefetched one step ahead; log/out deferred.
__global__ __launch_bounds__(512, 2) void k_scan(
        const int* __restrict__ obs, const float* __restrict__ lp2,
        const float* __restrict__ CM, const u32* __restrict__ PAu,
        const float* __restrict__ EX, float* __restrict__ out) {
    int b = blockIdx.x, tid = threadIdx.x;
    int w = tid >> 6, l = tid & 63;
    int h32 = (l >> 4) * 32;              // byte offset of this lane's B slice
    int r4 = (l >> 4) * 4;                // row group within a 16-row tile
    __shared__ unsigned char us8[NN] __attribute__((aligned(64)));
    __shared__ float rB[8] __attribute__((aligned(16)));
    __shared__ int obs_s[MM];
    if (tid < MM) obs_s[tid] = obs[b * MM + tid];

    // --- stage A-fragments: 16 x i32x8 per lane (4 tiles x 4 k-chunks) ---
    i32x8 pa[16];
#pragma unroll
    for (int ti = 0; ti < 4; ++ti)
#pragma unroll
        for (int kc = 0; kc < 4; ++kc)
            pa[ti * 4 + kc] = *(const i32x8*)(PAu
                + ((size_t)(((w * 4 + ti) * 4 + kc) * 64) + l) * 8);
#pragma unroll
    for (int q = 0; q < 16; ++q) asm volatile("" : "+a"(pa[q]));  // AGPR-resident

    float C_M = CM[0];
    int ubase[4];                          // publish byte addresses (u32-aligned)
#pragma unroll
    for (int ti = 0; ti < 4; ++ti) ubase[ti] = (w * 4 + ti) * 16 + r4;
    __syncthreads();                      // obs_s ready

    // ---- t = 0: e = EX[o0] * lp2 ----
    int o0 = obs_s[0];
    f32x4 e4[4];
    float loc = 0.f;
#pragma unroll
    for (int ti = 0; ti < 4; ++ti) {
        f32x4 ex  = *(const f32x4*)(EX  + (size_t)o0 * NN + (w * 4 + ti) * 16 + r4);
        f32x4 lpv = *(const f32x4*)(lp2 + (w * 4 + ti) * 16 + r4);
#pragma unroll
        for (int r = 0; r < 4; ++r) {
            float e = ex[r] * lpv[r];
            e4[ti][r] = e; loc += e;
        }
    }
    loc += __shfl_xor(loc, 16);
    loc += __shfl_xor(loc, 32);
    if (l == 0) rB[w] = loc;
    __syncthreads();                      // B1
    f32x4 sv0 = *(const f32x4*)rB;
    f32x4 sv1 = *(const f32x4*)(rB + 4);
    float S = (sv0[0] + sv0[1]) + (sv0[2] + sv0[3])
            + (sv1[0] + sv1[1]) + (sv1[2] + sv1[3]);
    S = fmaxf(S, 1e-35f);
    float sc = __builtin_amdgcn_rcpf(S) * 16.f;
    if ((l & 15) == 0) {
#pragma unroll
        for (int ti = 0; ti < 4; ++ti) {
            int d = 0;
            d = __builtin_amdgcn_cvt_pk_fp8_f32(e4[ti][0] * sc, e4[ti][1] * sc, d, false);
            d = __builtin_amdgcn_cvt_pk_fp8_f32(e4[ti][2] * sc, e4[ti][3] * sc, d, true);
            *(u32*)&us8[ubase[ti]] = (u32)d;
        }
    }
    __syncthreads();                      // B2: us8 ready
    float lS = __logf(S);
    if (tid == 0) out[(size_t)b * MM + 0] = lS;
    float K = C_M + lS;                   // Omega_1

    // prefetch t=1 emission row
    f32x4 exn[4];
    {
        int on = obs_s[1];
#pragma unroll
        for (int ti = 0; ti < 4; ++ti)
            exn[ti] = *(const f32x4*)(EX + (size_t)on * NN + (w * 4 + ti) * 16 + r4);
    }

    // ---- main scan t >= 1 ----
#pragma unroll 1
    for (int t = 1; t < MM; ++t) {
        const unsigned char* ub = us8;
        f32x4 a0 = {0.f,0.f,0.f,0.f}, a1 = {0.f,0.f,0.f,0.f};
        f32x4 a2 = {0.f,0.f,0.f,0.f}, a3 = {0.f,0.f,0.f,0.f};
        __builtin_amdgcn_s_setprio(1);
#pragma unroll
        for (int kc = 0; kc < 4; ++kc) {   // 4 x 32B LDS read, 16 MFMA total
            i32x8 bb = *(const i32x8*)(ub + kc * 128 + h32);
            a0 = __builtin_amdgcn_mfma_scale_f32_16x16x128_f8f6f4(
                     pa[0 * 4 + kc], bb, a0, 0, 0, 0, SCL1, 0, SCL1);
            a1 = __builtin_amdgcn_mfma_scale_f32_16x16x128_f8f6f4(
                     pa[1 * 4 + kc], bb, a1, 0, 0, 0, SCL1, 0, SCL1);
            a2 = __builtin_amdgcn_mfma_scale_f32_16x16x128_f8f6f4(
                     pa[2 * 4 + kc], bb, a2, 0, 0, 0, SCL1, 0, SCL1);
            a3 = __builtin_amdgcn_mfma_scale_f32_16x16x128_f8f6f4(
                     pa[3 * 4 + kc], bb, a3, 0, 0, 0, SCL1, 0, SCL1);
        }
        __builtin_amdgcn_s_setprio(0);
        f32x4 sacc[4] = { a0, a1, a2, a3 };

        // e = ex * s_raw (ex was prefetched last step)
        loc = 0.f;
#pragma unroll
        for (int ti = 0; ti < 4; ++ti)
#pragma unroll
            for (int r = 0; r < 4; ++r) {
                float e = exn[ti][r] * sacc[ti][r];
                e4[ti][r] = e; loc += e;
            }

        // prefetch t+1 emission row (hidden under reduce/barriers/publish)
        int on = obs_s[(t + 1 < MM) ? t + 1 : t];
#pragma unroll
        for (int ti = 0; ti < 4; ++ti)
            exn[ti] = *(const f32x4*)(EX + (size_t)on * NN + (w * 4 + ti) * 16 + r4);

        loc += __shfl_xor(loc, 16);
        loc += __shfl_xor(loc, 32);
        if (l == 0) rB[w] = loc;
        __syncthreads();                  // B1: rB ready (us8 reads done too)
        sv0 = *(const f32x4*)rB;
        sv1 = *(const f32x4*)(rB + 4);
        S = (sv0[0] + sv0[1]) + (sv0[2] + sv0[3])
          + (sv1[0] + sv1[1]) + (sv1[2] + sv1[3]);
        S = fmaxf(S, 1e-35f);
        sc = __builtin_amdgcn_rcpf(S) * 16.f;
        if ((l & 15) == 0) {
#pragma unroll
            for (int ti = 0; ti < 4; ++ti) {
                int d = 0;
                d = __builtin_amdgcn_cvt_pk_fp8_f32(e4[ti][0] * sc, e4[ti][1] * sc, d, false);
                d = __builtin_amdgcn_cvt_pk_fp8_f32(e4[ti][2] * sc, e4[ti][3] * sc, d, true);
                *(u32*)&us8[ubase[ti]] = (u32)d;
            }
        }
        __syncthreads();                  // B2: us8 ready for next step
        // deferred bookkeeping (overlaps next step's MFMA)
        float lSn = __logf(S);
        if (tid == 0) out[(size_t)b * MM + t] = K + lSn;
        K += C_M + lSn;                   // Omega_{t+1}
    }
}

extern "C" void kernel_launch(void* const* d_in, const int* in_sizes, int n_in,
                              void* d_out, int out_size, void* d_ws, size_t ws_size,
                              hipStream_t stream) {
    const int*   obs = (const int*)d_in[0];
    const float* pri = (const float*)d_in[1];
    const float* T   = (const float*)d_in[2];
    const float* E   = (const float*)d_in[3];
    float* out = (float*)d_out;
    char* ws = (char*)d_ws;

    float* c   = (float*)(ws + 0);
    float* lp2 = (float*)(ws + 2048);
    float* M   = (float*)(ws + 4096);
    float* CM  = (float*)(ws + 6144);
    u32*   PA  = (u32*)(ws + 8192);                       // 256 KB fp8 A-frags
    float* EX  = (float*)(ws + 8192 + 256 * 1024);        // 512 KB

    k_col_lse<<<8,   64, 0, stream>>>(T, c);
    k_rowM   <<<512, 64, 0, stream>>>(T, c, M);
    k_cm     <<<1,  512, 0, stream>>>(M, CM);
    k_priors <<<1,  512, 0, stream>>>(pri, M, CM, lp2);
    k_packA  <<<128, 64, 0, stream>>>(T, c, M, PA);
    k_rowEX  <<<512, 64, 0, stream>>>(E, M, CM, EX);
    k_scan   <<<BB, 512, 0, stream>>>(obs, lp2, CM, PA, EX, out);
}

// Round 14
// 327.062 us; speedup vs baseline: 1.5591x; 1.1946x over previous
//
#include <hip/hip_runtime.h>
#include <hip/hip_bf16.h>
#include <math.h>

#define NN 512   // hidden states
#define MM 256   // timesteps / emission symbols
#define BB 128   // batch

typedef float        f32x4 __attribute__((ext_vector_type(4)));
typedef unsigned int u32;
typedef u32          u32x2 __attribute__((ext_vector_type(2)));
typedef unsigned long long u64;
typedef int          i32x8 __attribute__((ext_vector_type(8)));

#define LOG16F 2.772588722239781f
#define SCL1   0x7F   // E8M0 scale byte = 1.0

__device__ __forceinline__ float wave_max(float v) {
#pragma unroll
    for (int o = 32; o > 0; o >>= 1) v = fmaxf(v, __shfl_xor(v, o));
    return v;
}
__device__ __forceinline__ float wave_sum(float v) {
#pragma unroll
    for (int o = 32; o > 0; o >>= 1) v += __shfl_xor(v, o);
    return v;
}

// ---------------- preprocessing (3 kernels) ----------------

// Column k logsumexp of T. grid 512 x 64 (one block per column).
__global__ void k_col_lse(const float* __restrict__ T, float* __restrict__ c) {
    int k = blockIdx.x, j = threadIdx.x;
    float m = -INFINITY, s = 0.f;
#pragma unroll
    for (int q = 0; q < 8; ++q) {
        float x = T[(q * 64 + j) * NN + k];
        if (x > m) { s = s * __expf(m - x) + 1.f; m = x; }
        else       { s += __expf(x - m); }
    }
    float mw = wave_max(m);
    float sw = wave_sum(s * __expf(m - mw));
    if (j == 0) c[k] = mw + __logf(sw);
}

// Row max: M[i] = max_k(T[i,k]-c[k]) - log(64). grid 512 x 64.
__global__ void k_rowM(const float* __restrict__ T, const float* __restrict__ c,
                       float* __restrict__ M) {
    int i = blockIdx.x, j = threadIdx.x;
    float mx = -INFINITY;
#pragma unroll
    for (int d = 0; d < 8; ++d) {
        int k = j * 8 + d;
        mx = fmaxf(mx, T[i * NN + k] - c[k]);
    }
    mx = wave_max(mx);
    if (j == 0) M[i] = mx - __logf(64.f);
}

// Fused prep: blocks 0..511 -> rowEX(i=blk); 512..639 -> packA(blk-512);
// 640 -> priors. C_M recomputed redundantly per block from M (8 loads+reduce).
__global__ void k_prep(const float* __restrict__ T, const float* __restrict__ c,
                       const float* __restrict__ M, const float* __restrict__ pr,
                       const float* __restrict__ E,
                       float* __restrict__ lp2, u32* __restrict__ PA,
                       float* __restrict__ EX) {
    int blk = blockIdx.x, l = threadIdx.x;
    if (blk < 512) {
        // ---- rowEX for row i = blk ----
        float mm = -INFINITY;
#pragma unroll
        for (int q = 0; q < 8; ++q) mm = fmaxf(mm, M[q * 64 + l]);
        float CMv = wave_max(mm);
        int i = blk;
        float v[4];
        float mx = -INFINITY;
#pragma unroll
        for (int d = 0; d < 4; ++d) {
            v[d] = E[i * MM + l * 4 + d];
            mx = fmaxf(mx, v[d]);
        }
        mx = wave_max(mx);
        float s = 0.f;
#pragma unroll
        for (int d = 0; d < 4; ++d) s += __expf(v[d] - mx);
        s = wave_sum(s);
        float lse = mx + __logf(s);
        float add = M[i] - CMv - LOG16F - lse;
#pragma unroll
        for (int d = 0; d < 4; ++d)
            EX[(size_t)(l * 4 + d) * NN + i] = __expf(v[d] + add);
    } else if (blk < 640) {
        // ---- packA: fp8 A-frags for mfma_scale 16x16x128, scaled x64 ----
        int bb = blk - 512;
        int tile = bb >> 2, kc = bb & 3;
        int row = tile * 16 + (l & 15);
        int kb  = kc * 128 + (l >> 4) * 32;
        float Mi = M[row];                // = rowmax - log64
        i32x8 dd;
#pragma unroll
        for (int q = 0; q < 8; ++q) {
            float p0 = __expf(T[row * NN + kb + 4*q + 0] - c[kb + 4*q + 0] - Mi);
            float p1 = __expf(T[row * NN + kb + 4*q + 1] - c[kb + 4*q + 1] - Mi);
            float p2 = __expf(T[row * NN + kb + 4*q + 2] - c[kb + 4*q + 2] - Mi);
            float p3 = __expf(T[row * NN + kb + 4*q + 3] - c[kb + 4*q + 3] - Mi);
            int d = 0;
            d = __builtin_amdgcn_cvt_pk_fp8_f32(p0, p1, d, false);
            d = __builtin_amdgcn_cvt_pk_fp8_f32(p2, p3, d, true);
            dd[q] = d;
        }
        *(i32x8*)(PA + ((size_t)bb * 64 + l) * 8) = dd;
    } else {
        // ---- priors: lp2[i] = exp(log_softmax(pr)[i] - M[i] + C_M + log16) ----
        float mm = -INFINITY;
#pragma unroll
        for (int q = 0; q < 8; ++q) mm = fmaxf(mm, M[q * 64 + l]);
        float CMv = wave_max(mm);
        float x[8];
        float mx = -INFINITY;
#pragma unroll
        for (int q = 0; q < 8; ++q) {
            x[q] = pr[q * 64 + l];
            mx = fmaxf(mx, x[q]);
        }
        mx = wave_max(mx);
        float s = 0.f;
#pragma unroll
        for (int q = 0; q < 8; ++q) s += __expf(x[q] - mx);
        s = wave_sum(s);
        float lse = mx + __logf(s);
#pragma unroll
        for (int q = 0; q < 8; ++q) {
            int i = q * 64 + l;
            lp2[i] = __expf(x[q] - lse - M[i] + CMv + LOG16F);
        }
    }
}

// ---------------- the scan (MX K=128 MFMA, r12-proven numerics) ----------------
// One block per batch, 512 threads = 8 waves. Wave w owns i-tiles w*4..w*4+3.
// 16 mfma_scale_f32_16x16x128_f8f6f4 per wave per step (scales = 1.0 exact),
// A-frags AGPR-resident, u-hat fp8 LINEAR in LDS. Fresh scale 16/S_t.
// EX prefetched one step ahead; log/out deferred past B2.
// 8 accumulators (kc-dep chains of 2) for MFMA latency hiding.
__global__ __launch_bounds__(512, 2) void k_scan(
        const int* __restrict__ obs, const float* __restrict__ lp2,
        const float* __restrict__ Mrow, const u32* __restrict__ PAu,
        const float* __restrict__ EX, float* __restrict__ out) {
    int b = blockIdx.x, tid = threadIdx.x;
    int w = tid >> 6, l = tid & 63;
    int h32 = (l >> 4) * 32;              // byte offset of this lane's B slice
    int r4 = (l >> 4) * 4;                // row group within a 16-row tile
    __shared__ unsigned char us8[NN] __attribute__((aligned(64)));
    __shared__ float rB[8] __attribute__((aligned(16)));
    __shared__ int obs_s[MM];
    if (tid < MM) obs_s[tid] = obs[b * MM + tid];

    // C_M redundant compute (8 loads + wave reduce; replaces k_cm kernel)
    float mm = -INFINITY;
#pragma unroll
    for (int q = 0; q < 8; ++q) mm = fmaxf(mm, Mrow[q * 64 + l]);
    float C_M = wave_max(mm);

    // --- stage A-fragments: 16 x i32x8 per lane (4 tiles x 4 k-chunks) ---
    i32x8 pa[16];
#pragma unroll
    for (int ti = 0; ti < 4; ++ti)
#pragma unroll
        for (int kc = 0; kc < 4; ++kc)
            pa[ti * 4 + kc] = *(const i32x8*)(PAu
                + ((size_t)(((w * 4 + ti) * 4 + kc) * 64) + l) * 8);
#pragma unroll
    for (int q = 0; q < 16; ++q) asm volatile("" : "+a"(pa[q]));  // AGPR-resident

    int ubase[4];
#pragma unroll
    for (int ti = 0; ti < 4; ++ti) ubase[ti] = (w * 4 + ti) * 16 + r4;
    __syncthreads();                      // obs_s ready

    // ---- t = 0: e = EX[o0] * lp2 ----
    int o0 = obs_s[0];
    f32x4 e4[4];
    float loc = 0.f;
#pragma unroll
    for (int ti = 0; ti < 4; ++ti) {
        f32x4 ex  = *(const f32x4*)(EX  + (size_t)o0 * NN + (w * 4 + ti) * 16 + r4);
        f32x4 lpv = *(const f32x4*)(lp2 + (w * 4 + ti) * 16 + r4);
#pragma unroll
        for (int r = 0; r < 4; ++r) {
            float e = ex[r] * lpv[r];
            e4[ti][r] = e; loc += e;
        }
    }
    loc += __shfl_xor(loc, 16);
    loc += __shfl_xor(loc, 32);
    if (l == 0) rB[w] = loc;
    __syncthreads();                      // B1
    f32x4 sv0 = *(const f32x4*)rB;
    f32x4 sv1 = *(const f32x4*)(rB + 4);
    float S = (sv0[0] + sv0[1]) + (sv0[2] + sv0[3])
            + (sv1[0] + sv1[1]) + (sv1[2] + sv1[3]);
    S = fmaxf(S, 1e-35f);
    float sc = __builtin_amdgcn_rcpf(S) * 16.f;
    if ((l & 15) == 0) {
#pragma unroll
        for (int ti = 0; ti < 4; ++ti) {
            int d = 0;
            d = __builtin_amdgcn_cvt_pk_fp8_f32(e4[ti][0] * sc, e4[ti][1] * sc, d, false);
            d = __builtin_amdgcn_cvt_pk_fp8_f32(e4[ti][2] * sc, e4[ti][3] * sc, d, true);
            *(u32*)&us8[ubase[ti]] = (u32)d;
        }
    }
    __syncthreads();                      // B2: us8 ready
    float lS = __logf(S);
    if (tid == 0) out[(size_t)b * MM + 0] = lS;
    float K = C_M + lS;                   // Omega_1

    // prefetch t=1 emission row
    f32x4 exn[4];
    {
        int on = obs_s[1];
#pragma unroll
        for (int ti = 0; ti < 4; ++ti)
            exn[ti] = *(const f32x4*)(EX + (size_t)on * NN + (w * 4 + ti) * 16 + r4);
    }

    // ---- main scan t >= 1 ----
#pragma unroll 1
    for (int t = 1; t < MM; ++t) {
        const unsigned char* ub = us8;
        f32x4 a0 = {0.f,0.f,0.f,0.f}, a1 = {0.f,0.f,0.f,0.f};
        f32x4 a2 = {0.f,0.f,0.f,0.f}, a3 = {0.f,0.f,0.f,0.f};
        f32x4 b0 = {0.f,0.f,0.f,0.f}, b1 = {0.f,0.f,0.f,0.f};
        f32x4 b2 = {0.f,0.f,0.f,0.f}, b3 = {0.f,0.f,0.f,0.f};
        __builtin_amdgcn_s_setprio(1);
#pragma unroll
        for (int kc = 0; kc < 2; ++kc) {   // chains of depth 2 (8 accumulators)
            i32x8 bbA = *(const i32x8*)(ub + kc * 128 + h32);
            i32x8 bbB = *(const i32x8*)(ub + (kc + 2) * 128 + h32);
            a0 = __builtin_amdgcn_mfma_scale_f32_16x16x128_f8f6f4(
                     pa[0 * 4 + kc], bbA, a0, 0, 0, 0, SCL1, 0, SCL1);
            a1 = __builtin_amdgcn_mfma_scale_f32_16x16x128_f8f6f4(
                     pa[1 * 4 + kc], bbA, a1, 0, 0, 0, SCL1, 0, SCL1);
            a2 = __builtin_amdgcn_mfma_scale_f32_16x16x128_f8f6f4(
                     pa[2 * 4 + kc], bbA, a2, 0, 0, 0, SCL1, 0, SCL1);
            a3 = __builtin_amdgcn_mfma_scale_f32_16x16x128_f8f6f4(
                     pa[3 * 4 + kc], bbA, a3, 0, 0, 0, SCL1, 0, SCL1);
            b0 = __builtin_amdgcn_mfma_scale_f32_16x16x128_f8f6f4(
                     pa[0 * 4 + kc + 2], bbB, b0, 0, 0, 0, SCL1, 0, SCL1);
            b1 = __builtin_amdgcn_mfma_scale_f32_16x16x128_f8f6f4(
                     pa[1 * 4 + kc + 2], bbB, b1, 0, 0, 0, SCL1, 0, SCL1);
            b2 = __builtin_amdgcn_mfma_scale_f32_16x16x128_f8f6f4(
                     pa[2 * 4 + kc + 2], bbB, b2, 0, 0, 0, SCL1, 0, SCL1);
            b3 = __builtin_amdgcn_mfma_scale_f32_16x16x128_f8f6f4(
                     pa[3 * 4 + kc + 2], bbB, b3, 0, 0, 0, SCL1, 0, SCL1);
        }
        __builtin_amdgcn_s_setprio(0);
        f32x4 sacc[4] = { a0 + b0, a1 + b1, a2 + b2, a3 + b3 };

        // e = ex * s_raw (ex was prefetched last step)
        loc = 0.f;
#pragma unroll
        for (int ti = 0; ti < 4; ++ti)
#pragma unroll
            for (int r = 0; r < 4; ++r) {
                float e = exn[ti][r] * sacc[ti][r];
                e4[ti][r] = e; loc += e;
            }

        // prefetch t+1 emission row (hidden under reduce/barriers/publish)
        int on = obs_s[(t + 1 < MM) ? t + 1 : t];
#pragma unroll
        for (int ti = 0; ti < 4; ++ti)
            exn[ti] = *(const f32x4*)(EX + (size_t)on * NN + (w * 4 + ti) * 16 + r4);

        loc += __shfl_xor(loc, 16);
        loc += __shfl_xor(loc, 32);
        if (l == 0) rB[w] = loc;
        __syncthreads();                  // B1: rB ready (us8 reads done too)
        sv0 = *(const f32x4*)rB;
        sv1 = *(const f32x4*)(rB + 4);
        S = (sv0[0] + sv0[1]) + (sv0[2] + sv0[3])
          + (sv1[0] + sv1[1]) + (sv1[2] + sv1[3]);
        S = fmaxf(S, 1e-35f);
        sc = __builtin_amdgcn_rcpf(S) * 16.f;
        if ((l & 15) == 0) {
#pragma unroll
            for (int ti = 0; ti < 4; ++ti) {
                int d = 0;
                d = __builtin_amdgcn_cvt_pk_fp8_f32(e4[ti][0] * sc, e4[ti][1] * sc, d, false);
                d = __builtin_amdgcn_cvt_pk_fp8_f32(e4[ti][2] * sc, e4[ti][3] * sc, d, true);
                *(u32*)&us8[ubase[ti]] = (u32)d;
            }
        }
        __syncthreads();                  // B2: us8 ready for next step
        // deferred bookkeeping (overlaps next step's MFMA)
        float lSn = __logf(S);
        if (tid == 0) out[(size_t)b * MM + t] = K + lSn;
        K += C_M + lSn;                   // Omega_{t+1}
    }
}

extern "C" void kernel_launch(void* const* d_in, const int* in_sizes, int n_in,
                              void* d_out, int out_size, void* d_ws, size_t ws_size,
                              hipStream_t stream) {
    const int*   obs = (const int*)d_in[0];
    const float* pri = (const float*)d_in[1];
    const float* T   = (const float*)d_in[2];
    const float* E   = (const float*)d_in[3];
    float* out = (float*)d_out;
    char* ws = (char*)d_ws;

    float* c   = (float*)(ws + 0);
    float* lp2 = (float*)(ws + 2048);
    float* M   = (float*)(ws + 4096);
    u32*   PA  = (u32*)(ws + 8192);                       // 256 KB fp8 A-frags
    float* EX  = (float*)(ws + 8192 + 256 * 1024);        // 512 KB

    k_col_lse<<<512, 64, 0, stream>>>(T, c);
    k_rowM   <<<512, 64, 0, stream>>>(T, c, M);
    k_prep   <<<641, 64, 0, stream>>>(T, c, M, pri, E, lp2, PA, EX);
    k_scan   <<<BB, 512, 0, stream>>>(obs, lp2, M, PA, EX, out);
}